// Round 1
// 188.171 us; speedup vs baseline: 1.0543x; 1.0543x over previous
//
#include <hip/hip_runtime.h>
#include <hip/hip_fp16.h>
#include <cstddef>
#include <cstdint>

#define DIM 128
#define SEQ 2048
#define NB 32
#define NCH 512
#define NROWS (NB * SEQ)          // 65536

typedef _Float16 half8 __attribute__((ext_vector_type(8)));
typedef float    f32x4 __attribute__((ext_vector_type(4)));

// ws layout: cmb fp16 [NROWS][NCH] | Wfg fp16 frag-linear [65536]
#define CMB_BYTES ((size_t)NROWS * NCH * 2)       // 67,108,864
#define WFG_OFF   CMB_BYTES
#define WFG_BYTES ((size_t)NCH * DIM * 2)         // 131,072
#define WS_NEEDED (WFG_OFF + WFG_BYTES)           // ~64.1 MB (proven available)

// fast sigmoid: raw v_exp + raw v_rcp (no Newton refinement)
__device__ __forceinline__ float sigf(float v) {
    return __builtin_amdgcn_rcpf(1.0f + __builtin_amdgcn_exp2f(v * -1.44269504f));
}

// packed fp32x8 -> fp16x8 via v_cvt_pkrtz_f16_f32 (4 instrs, no pack movs)
__device__ __forceinline__ half8 cvt8(float4 v0, float4 v1) {
    auto p0 = __builtin_amdgcn_cvt_pkrtz(v0.x, v0.y);
    auto p1 = __builtin_amdgcn_cvt_pkrtz(v0.z, v0.w);
    auto p2 = __builtin_amdgcn_cvt_pkrtz(v1.x, v1.y);
    auto p3 = __builtin_amdgcn_cvt_pkrtz(v1.z, v1.w);
    union U { half8 h8; decltype(p0) p[4]; } u;
    u.p[0] = p0; u.p[1] = p1; u.p[2] = p2; u.p[3] = p3;
    return u.h8;
}

// ---------------------------------------------------------------------------
// k0: Wfg = Wf (fp16) pre-swizzled into MFMA B-fragment linear layout.
// ---------------------------------------------------------------------------
__global__ void k0_wfg(const float* __restrict__ Wf, _Float16* __restrict__ Wfg) {
    int t = blockIdx.x * 256 + threadIdx.x;       // 8192 threads x 8 elems
#pragma unroll
    for (int i = 0; i < 8; ++i) {
        int o = t * 8 + i;                         // 65536 total
        int j    = o & 7;
        int lane = (o >> 3) & 63;
        int q    = lane >> 4, n16 = lane & 15;
        int ct   = (o >> 9) & 7;
        int ks   = (o >> 12) & 1;
        int kb   = o >> 13;
        int k = kb * 64 + ks * 32 + q * 8 + j;
        int n = ct * 16 + n16;
        Wfg[o] = (_Float16)Wf[n * NCH + k];
    }
}

// ---------------------------------------------------------------------------
// kfused v9: same R8 structure as v8 (32ch/block, 512 thr, grid 32x16,
//   A-frag software pipeline, 2 barriers/tile) with:
//   - __launch_bounds__(512,2): grid is 2 blocks/CU anyway; frees VGPRs
//     (v8's 56-VGPR throttle forced the scan into a serial LDS-latency chain)
//   - grouped-prefetch scan: 16x ds_read_b64 hoisted into regs, then the
//     dependent fmaf chain (breaks the ~120cyc/step latency serialization)
//   - raw-rcp sigmoid / raw sqrt / packed cvt_pkrtz conversions
// ---------------------------------------------------------------------------
__global__ __launch_bounds__(512, 2) void kfused(
        const float* __restrict__ x,
        const float* __restrict__ Wa_u, const float* __restrict__ ba_u,
        const float* __restrict__ Wi_u, const float* __restrict__ bi_u,
        const float* __restrict__ g_u,
        const float* __restrict__ Wa_w, const float* __restrict__ ba_w,
        const float* __restrict__ Wi_w, const float* __restrict__ bi_w,
        const float* __restrict__ g_w,
        _Float16* __restrict__ cmb) {
    __shared__ _Float16 Bs[8192];        // [ks(4)][nt(4)][lane(64)][8] = 16 KB
    __shared__ float2   seg[32][33];     // (A,U) per (segment, channel)
    __shared__ float    pref[32][33];    // incoming h per (segment, channel)
    __shared__ float    carry[32];

    const int tid  = threadIdx.x;
    const int lane = tid & 63;
    const int w    = tid >> 6;           // wave 0..7 = m-tile (16 s each)
    const int quad = lane >> 4;
    const int n16  = lane & 15;

    const int b  = blockIdx.x;           // 0..31
    const int cg = blockIdx.y;           // 0..15
    const int p  = cg >> 3;              // path
    const int ebase = (cg & 7) * 32;     // 32 channels per block

    const float* Wa  = p ? Wa_w : Wa_u;
    const float* Wi  = p ? Wi_w : Wi_u;
    const float* bap = p ? ba_w : ba_u;
    const float* bip = p ? bi_w : bi_u;
    const float* gp  = p ? g_w  : g_u;

    // ---- stage Bs once: slot sl = ks*256 + nt*64 + l (1024 slots, 2/thread)
    for (int sl = tid; sl < 1024; sl += 512) {
        int l  = sl & 63;
        int nt = (sl >> 6) & 3;
        int ks = sl >> 8;
        int qq = l >> 4, nn = l & 15;
        int e = ebase + (nt & 1) * 16 + nn;
        const float* Wp = (nt >> 1) ? Wi : Wa;
        const float* src = Wp + (size_t)e * DIM + ks * 32 + qq * 8;
        float4 v0 = *(const float4*)src;
        float4 v1 = *(const float4*)(src + 4);
        *(half8*)&Bs[sl * 8] = cvt8(v0, v1);
    }

    // per-thread channel params (hh = 0/1 -> cc = hh*16 + n16)
    float rba[2], rbi[2], ral[2];
#pragma unroll
    for (int hh = 0; hh < 2; ++hh) {
        int e = ebase + hh * 16 + n16;
        rba[hh] = bap[e];
        rbi[hh] = bip[e];
        ral[hh] = sigf(gp[e]);
    }
    if (tid < 32) carry[tid] = 0.0f;

    // incremental recency weight: sc(s) = exp(3s/2047)
    float scb = __expf((float)(w * 16 + quad * 4) * (3.0f / 2047.0f));
    const float r1    = __expf(3.0f / 2047.0f);
    const float r2    = r1 * r1;
    const float r3    = r2 * r1;
    const float cs128 = __expf(128.0f * 3.0f / 2047.0f);

    // A-row for this lane: s_local = w*16 + n16 (= MFMA m index)
    const float* xbase = x + ((size_t)b * SEQ + (size_t)(w * 16 + n16)) * DIM + quad * 8;
    _Float16* cmbb = cmb + (size_t)b * SEQ * NCH + cg * 32 + n16;

    __syncthreads();

    // ---- prologue: load + convert tile 0's A-frags ----
    half8 af[4];
    {
        float4 xf0[8];
#pragma unroll
        for (int ks = 0; ks < 4; ++ks) {
            xf0[2 * ks]     = *(const float4*)(xbase + ks * 32);
            xf0[2 * ks + 1] = *(const float4*)(xbase + ks * 32 + 4);
        }
#pragma unroll
        for (int ks = 0; ks < 4; ++ks)
            af[ks] = cvt8(xf0[2 * ks], xf0[2 * ks + 1]);
    }

    for (int t = 0; t < 16; ++t) {
        const int s0 = t * 128;

        // ---- MFMA: 4 n-tiles, K=128 (uses af, ready from last tile) ----
        f32x4 acc[4];
#pragma unroll
        for (int nt = 0; nt < 4; ++nt) acc[nt] = (f32x4){0.f, 0.f, 0.f, 0.f};
#pragma unroll
        for (int ks = 0; ks < 4; ++ks) {
            half8 a = af[ks];
#pragma unroll
            for (int nt = 0; nt < 4; ++nt) {
                half8 bb = *(const half8*)&Bs[(ks * 256 + nt * 64 + lane) * 8];
                acc[nt] = __builtin_amdgcn_mfma_f32_16x16x32_f16(a, bb, acc[nt], 0, 0, 0);
            }
        }

        // ---- issue next tile's A loads NOW (fly across gates/compose) ----
        float4 xf[8];
        {
            int tn = (t + 1) & 15;
            const float* ab = xbase + (size_t)tn * 128 * DIM;
#pragma unroll
            for (int ks = 0; ks < 4; ++ks) {
                xf[2 * ks]     = *(const float4*)(ab + ks * 32);
                xf[2 * ks + 1] = *(const float4*)(ab + ks * 32 + 4);
            }
        }

        // ---- gates + 4-step affine compose (2 channels) ----
        float sc[4];
        if (p) { sc[0] = scb; sc[1] = scb * r1; sc[2] = scb * r2; sc[3] = scb * r3; }
        else   { sc[0] = sc[1] = sc[2] = sc[3] = 1.0f; }
        scb *= cs128;

        float a_s[2][4], u_s[2][4];
#pragma unroll
        for (int hh = 0; hh < 2; ++hh) {
            float A4 = 1.0f, U4 = 0.0f;
#pragma unroll
            for (int reg = 0; reg < 4; ++reg) {
                float pa = fmaf(acc[hh][reg],     sc[reg], rba[hh]);
                float pi = fmaf(acc[2 + hh][reg], sc[reg], rbi[hh]);
                float rst = sigf(pa);
                float ig  = sigf(pi);
                float a   = ral[hh] * __builtin_amdgcn_exp2f(-rst * 1.5849625007211562f);
                float m   = fmaxf(fmaf(-a, a, 1.0f), 0.0f);
                float u   = __builtin_amdgcn_sqrtf(m) * (ig * pi);
                a_s[hh][reg] = a; u_s[hh][reg] = u;
                A4 *= a;
                U4 = fmaf(a, U4, u);
            }
            seg[w * 4 + quad][hh * 16 + n16] = make_float2(A4, U4);
        }
        __syncthreads();   // barrier 1: seg visible

        // ---- scan window: wave-0 lanes scan (grouped-prefetch, breaks the
        //      per-step LDS latency chain); everyone converts xf -> af ----
        if (tid < 32) {
            float H = carry[tid];
#pragma unroll
            for (int g = 0; g < 2; ++g) {
                float2 sv[16];
#pragma unroll
                for (int j = 0; j < 16; ++j)
                    sv[j] = seg[g * 16 + j][tid];
#pragma unroll
                for (int j = 0; j < 16; ++j) {
                    pref[g * 16 + j][tid] = H;
                    H = fmaf(sv[j].x, H, sv[j].y);
                }
            }
            carry[tid] = H;
        }
        // convert next tile's A data in the otherwise-idle scan window
#pragma unroll
        for (int ks = 0; ks < 4; ++ks)
            af[ks] = cvt8(xf[2 * ks], xf[2 * ks + 1]);
        __builtin_amdgcn_sched_barrier(0);   // pin loads+convert here
        __syncthreads();   // barrier 2: pref/carry visible

        // ---- replay + direct store (2B/lane, 16-lane = 32B segments) ----
#pragma unroll
        for (int hh = 0; hh < 2; ++hh) {
            float h = pref[w * 4 + quad][hh * 16 + n16];
            _Float16* dst = cmbb + (size_t)(s0 + w * 16 + quad * 4) * NCH + hh * 16;
#pragma unroll
            for (int reg = 0; reg < 4; ++reg) {
                h = fmaf(a_s[hh][reg], h, u_s[hh][reg]);
                dst[(size_t)reg * NCH] = (_Float16)h;
            }
        }
    }
}

// ---------------------------------------------------------------------------
// k3: round-3 structure VERBATIM: 128-row tile, 64-wide K pages,
//     32 MFMA/barrier, grid 512 = 2 blocks/CU.
// ---------------------------------------------------------------------------
__global__ __launch_bounds__(256, 2) void k3_mfma(
        const _Float16* __restrict__ cmb, const _Float16* __restrict__ Wfg,
        const float* __restrict__ bfv, float* __restrict__ out) {
    __shared__ _Float16 As[16 * 512];
    __shared__ _Float16 Bs[16 * 512];

    const int tid  = threadIdx.x;
    const int lane = tid & 63;
    const int w    = tid >> 6;
    const int row0 = blockIdx.x * 128;
    const int q    = lane >> 4;
    const int nn   = lane & 15;

    f32x4 acc[2][8];
#pragma unroll
    for (int rt = 0; rt < 2; ++rt)
#pragma unroll
        for (int ct = 0; ct < 8; ++ct)
            acc[rt][ct] = (f32x4){0.0f, 0.0f, 0.0f, 0.0f};

    for (int kb = 0; kb < 8; ++kb) {
        const int kc = kb * 64;
#pragma unroll
        for (int i = 0; i < 4; ++i) {
            int f = tid + i * 256;
            int r = f >> 3, k8 = f & 7;
            uint4 v = *(const uint4*)(cmb + (size_t)(row0 + r) * NCH + kc + k8 * 8);
            int rt = r >> 4, m = r & 15, ks = k8 >> 2, qq = k8 & 3;
            *(uint4*)&As[(((rt * 2 + ks) * 64) + qq * 16 + m) * 8] = v;
        }
#pragma unroll
        for (int i = 0; i < 4; ++i) {
            int f = tid + i * 256;
            uint4 v = *(const uint4*)(Wfg + (size_t)kb * 8192 + (size_t)f * 8);
            *(uint4*)&Bs[(size_t)f * 8] = v;
        }
        __syncthreads();

#pragma unroll
        for (int ks = 0; ks < 2; ++ks) {
            half8 a0 = *(const half8*)&As[(((w * 2 + 0) * 2 + ks) * 512) + lane * 8];
            half8 a1 = *(const half8*)&As[(((w * 2 + 1) * 2 + ks) * 512) + lane * 8];
#pragma unroll
            for (int ct = 0; ct < 8; ++ct) {
                half8 bb = *(const half8*)&Bs[((ks * 8 + ct) * 512) + lane * 8];
                acc[0][ct] = __builtin_amdgcn_mfma_f32_16x16x32_f16(a0, bb, acc[0][ct], 0, 0, 0);
                acc[1][ct] = __builtin_amdgcn_mfma_f32_16x16x32_f16(a1, bb, acc[1][ct], 0, 0, 0);
            }
        }
        __syncthreads();
    }

#pragma unroll
    for (int rt = 0; rt < 2; ++rt) {
        int rbase = row0 + w * 32 + rt * 16 + q * 4;
#pragma unroll
        for (int ct = 0; ct < 8; ++ct) {
            int col = ct * 16 + nn;
            float bias = bfv[col];
#pragma unroll
            for (int reg = 0; reg < 4; ++reg)
                out[(size_t)(rbase + reg) * DIM + col] = acc[rt][ct][reg] + bias;
        }
    }
}

// ---------------------------------------------------------------------------
extern "C" void kernel_launch(void* const* d_in, const int* in_sizes, int n_in,
                              void* d_out, int out_size, void* d_ws, size_t ws_size,
                              hipStream_t stream) {
    if (ws_size < WS_NEEDED) return;

    const float* x    = (const float*)d_in[0];
    const float* Wa_u = (const float*)d_in[1];
    const float* ba_u = (const float*)d_in[2];
    const float* Wi_u = (const float*)d_in[3];
    const float* bi_u = (const float*)d_in[4];
    const float* g_u  = (const float*)d_in[5];
    const float* Wa_w = (const float*)d_in[6];
    const float* ba_w = (const float*)d_in[7];
    const float* Wi_w = (const float*)d_in[8];
    const float* bi_w = (const float*)d_in[9];
    const float* g_w  = (const float*)d_in[10];
    const float* Wf   = (const float*)d_in[11];
    const float* bfv  = (const float*)d_in[12];
    float* out = (float*)d_out;

    char* ws = (char*)d_ws;
    _Float16* cmb = (_Float16*)ws;
    _Float16* Wfg = (_Float16*)(ws + WFG_OFF);

    hipLaunchKernelGGL(k0_wfg, dim3(32), dim3(256), 0, stream, Wf, Wfg);
    hipLaunchKernelGGL(kfused, dim3(32, 16), dim3(512), 0, stream,
                       x, Wa_u, ba_u, Wi_u, bi_u, g_u,
                       Wa_w, ba_w, Wi_w, bi_w, g_w, cmb);
    hipLaunchKernelGGL(k3_mfma, dim3(512), dim3(256), 0, stream,
                       cmb, Wfg, bfv, out);
}